// Round 5
// baseline (157.026 us; speedup 1.0000x reference)
//
#include <hip/hip_runtime.h>
#include <stdint.h>

#define D 2048
#define R 64
#define M_TOTAL 8192

typedef float f32x4 __attribute__((ext_vector_type(4)));
typedef __bf16 bf16x8 __attribute__((ext_vector_type(8)));
typedef unsigned short u16x8 __attribute__((ext_vector_type(8)));
typedef unsigned short u16x4 __attribute__((ext_vector_type(4)));

__device__ __forceinline__ unsigned short f2bf(float f) {
  unsigned u = __builtin_bit_cast(unsigned, f);
  u += 0x7FFFu + ((u >> 16) & 1u);
  return (unsigned short)(u >> 16);
}

__device__ __forceinline__ void gload_lds16(const void* g, void* l) {
  __builtin_amdgcn_global_load_lds(
      (const __attribute__((address_space(1))) void*)g,
      (__attribute__((address_space(3))) void*)l, 16, 0, 0);
}

// ---------------- fused prep (512 threads/block) ----------------
// blocks 0..127  : h = bf16(gelu(x@W1^T+b1)) from x f32 directly, ALSO writes xbf.
//                  8 waves = 2 K-halves x 4 row-groups; 32-iter loop, 2-iter
//                  register prefetch, XOR-swizzled LDS, end reduce over K-halves.
// blocks 128..639: St[n][k] = bf16(A[k][n]+B[k][n]+C[k][n]), 128x64 tiles.
// blocks 640..643: W2 f32->bf16.
__global__ __launch_bounds__(512) void prep_kernel(
    const float* __restrict__ x, const float* __restrict__ A,
    const float* __restrict__ B, const float* __restrict__ C,
    const float* __restrict__ w1, const float* __restrict__ b1,
    const float* __restrict__ w2,
    unsigned short* __restrict__ xbf, unsigned short* __restrict__ st,
    unsigned short* __restrict__ w2bf, unsigned short* __restrict__ hbf) {
  __shared__ unsigned short plds[16384];  // 32 KB shared by roles
  const int t = threadIdx.x;
  const int bx = blockIdx.x;

  if (bx < 128) {
    // ---- h + x-conv ----
    unsigned short* sX = plds;         // [kh][buf][64 rows][32 k] = 8192 shorts
    unsigned short* sW = plds + 8192;
    const int m0 = bx * 64;
    // staging view: thread t -> half kh = t>>8, row = (t&255)>>2, granule c = t&3
    const int kh = t >> 8;
    const int row = (t & 255) >> 2;
    const int c = t & 3;
    const float* xp = x + (size_t)(m0 + row) * D + kh * 1024 + c * 8;
    const float* wp = w1 + (size_t)row * D + kh * 1024 + c * 8;
    unsigned short* xop = xbf + (size_t)(m0 + row) * D + kh * 1024 + c * 8;
    const int wslot = (c ^ ((row >> 1) & 3)) * 8;
    unsigned short* sXw = sX + kh * 4096 + row * 32 + wslot;
    unsigned short* sWw = sW + kh * 4096 + row * 32 + wslot;
    // MFMA view: wave w -> half khw = w>>2, row-group wg = w&3
    const int w = t >> 6, l = t & 63, lm = l & 15, lk = l >> 4;
    const int khw = w >> 2, wg = w & 3;
    const int rslot = (lk ^ ((lm >> 1) & 3)) * 8;
    const unsigned short* sXr = sX + khw * 4096 + (wg * 16 + lm) * 32 + rslot;
    const unsigned short* sWr = sW + khw * 4096 + lm * 32 + rslot;

    f32x4 acc[4] = {};
    float4 rx[2][2], rw[2][2];
    rx[0][0] = *(const float4*)(xp);      rx[0][1] = *(const float4*)(xp + 4);
    rw[0][0] = *(const float4*)(wp);      rw[0][1] = *(const float4*)(wp + 4);
    rx[1][0] = *(const float4*)(xp + 32); rx[1][1] = *(const float4*)(xp + 36);
    rw[1][0] = *(const float4*)(wp + 32); rw[1][1] = *(const float4*)(wp + 36);

#pragma unroll 1
    for (int kt = 0; kt < 32; ++kt) {
      const int s = kt & 1;
      const int buf = s * 2048;
      u16x8 ox = { f2bf(rx[s][0].x), f2bf(rx[s][0].y), f2bf(rx[s][0].z), f2bf(rx[s][0].w),
                   f2bf(rx[s][1].x), f2bf(rx[s][1].y), f2bf(rx[s][1].z), f2bf(rx[s][1].w) };
      u16x8 ow = { f2bf(rw[s][0].x), f2bf(rw[s][0].y), f2bf(rw[s][0].z), f2bf(rw[s][0].w),
                   f2bf(rw[s][1].x), f2bf(rw[s][1].y), f2bf(rw[s][1].z), f2bf(rw[s][1].w) };
      *(u16x8*)(sXw + buf) = ox;
      *(u16x8*)(sWw + buf) = ow;
      *(u16x8*)(xop + kt * 32) = ox;
      if (kt + 2 < 32) {  // prefetch 2 iters ahead into the set just consumed
        rx[s][0] = *(const float4*)(xp + (kt + 2) * 32);
        rx[s][1] = *(const float4*)(xp + (kt + 2) * 32 + 4);
        rw[s][0] = *(const float4*)(wp + (kt + 2) * 32);
        rw[s][1] = *(const float4*)(wp + (kt + 2) * 32 + 4);
      }
      __syncthreads();
      bf16x8 a = __builtin_bit_cast(bf16x8, *(const u16x8*)(sXr + buf));
#pragma unroll
      for (int j = 0; j < 4; ++j) {
        bf16x8 b = __builtin_bit_cast(bf16x8, *(const u16x8*)(sWr + buf + j * 512));
        acc[j] = __builtin_amdgcn_mfma_f32_16x16x32_bf16(a, b, acc[j], 0, 0, 0);
      }
    }

    // reduce K-halves: layout [j][wg*64+l] f32x4 (conflict-free, 16 KB)
    __syncthreads();
    float* red = (float*)plds;
    if (khw == 1) {
#pragma unroll
      for (int j = 0; j < 4; ++j)
        *(f32x4*)(red + (j * 256 + wg * 64 + l) * 4) = acc[j];
    }
    __syncthreads();
    if (khw == 0) {
      int m_base = m0 + wg * 16 + lk * 4;
#pragma unroll
      for (int j = 0; j < 4; ++j) {
        f32x4 o = *(const f32x4*)(red + (j * 256 + wg * 64 + l) * 4);
        int n = j * 16 + lm;
        float bv = b1[n];
#pragma unroll
        for (int r = 0; r < 4; ++r) {
          float v = acc[j][r] + o[r] + bv;
          float g = 0.5f * v * (1.0f + erff(v * 0.70710678118654752f));
          hbf[(size_t)(m_base + r) * R + n] = f2bf(g);
        }
      }
    }
  } else if (bx < 640) {
    // ---- sumt: 128(k) x 64(n) tiles ----
    unsigned short (*lds)[68] = (unsigned short(*)[68])plds;
    const int id = bx - 128;
    const int k0 = (id >> 5) * 128, n0 = (id & 31) * 64;
#pragma unroll
    for (int q = 0; q < 4; ++q) {
      int rowq = q * 32 + (t >> 4);
      int col = (t & 15) * 4;
      size_t off = (size_t)(k0 + rowq) * D + n0 + col;
      float4 a = *(const float4*)(A + off);
      float4 b = *(const float4*)(B + off);
      float4 cc = *(const float4*)(C + off);
      u16x4 o = { f2bf(a.x + b.x + cc.x), f2bf(a.y + b.y + cc.y),
                  f2bf(a.z + b.z + cc.z), f2bf(a.w + b.w + cc.w) };
      *(u16x4*)(&lds[rowq][col]) = o;
    }
    __syncthreads();
    const int n = t >> 3, kc = (t & 7) * 16;
    u16x8 v0, v1;
#pragma unroll
    for (int jj = 0; jj < 8; ++jj) v0[jj] = lds[kc + jj][n];
#pragma unroll
    for (int jj = 0; jj < 8; ++jj) v1[jj] = lds[kc + 8 + jj][n];
    size_t ooff = (size_t)(n0 + n) * D + k0 + kc;
    *(u16x8*)(st + ooff) = v0;
    *(u16x8*)(st + ooff + 8) = v1;
  } else {
    // ---- W2 conv ----
    const int NW4 = (D * R) / 4;  // 32768
    for (int i = (bx - 640) * 512 + t; i < NW4; i += 4 * 512) {
      float4 v = ((const float4*)w2)[i];
      u16x4 o = { f2bf(v.x), f2bf(v.y), f2bf(v.z), f2bf(v.w) };
      *(u16x4*)(w2bf + (size_t)i * 4) = o;
    }
  }
}

// ---------------- main: out = (x @ S) * dt + Dp ----------------
// 256x256 tile, BK=64, 8 waves (2M x 4N), 4-phase schedule. All 4 half-tiles
// of tile kt+1 staged EARLY in tile kt (A0,A1 @P0; B0 @P1; B1 @P2) so the
// single end-of-tile drain has >=1.5 phases of issue-to-wait distance.
__global__ __launch_bounds__(512, 2) void gemm_kernel(
    const unsigned short* __restrict__ xbf, const unsigned short* __restrict__ st,
    const unsigned short* __restrict__ hbf, const unsigned short* __restrict__ w2bf,
    const float* __restrict__ b2, const float* __restrict__ dp,
    float* __restrict__ out) {
  __shared__ unsigned short sA[2 * 16384];  // 2 bufs x 256 rows x 64 k, 64 KB
  __shared__ unsigned short sB[2 * 16384];  // 64 KB
  const int tid = threadIdx.x;
  const int w = tid >> 6, l = tid & 63, lk = l >> 4, lm = l & 15;
  const int wm = w >> 2, wn = w & 3;
  int bid = blockIdx.x;
  int wg = (bid & 7) * 32 + (bid >> 3);  // bijective XCD swizzle (256 wgs)
  int mb = wg >> 3, nb = wg & 7;
  int m0 = mb * 256, n0 = nb * 256;

  const int kg = (tid & 7) ^ ((tid >> 3) & 7);
  const unsigned short* gA = xbf + (size_t)(m0 + (tid >> 3)) * D + kg * 8;
  const unsigned short* gB = st + (size_t)(n0 + (tid >> 3)) * D + kg * 8;
  const int dstw = w * 512;  // shorts; wave-uniform base (HW adds lane*16B)

  const int s7 = lm & 7;
  const int gsw0 = (lk ^ s7) * 8;        // kk=0
  const int gsw1 = ((4 | lk) ^ s7) * 8;  // kk=1
  const int arow = (wm * 128 + lm) * 64;
  const int brow = (wn * 64 + lm) * 64;

  f32x4 acc[8][4] = {};

#define STAGE(gptr, sbuf, T, h) do { \
    const unsigned short* g_ = (gptr) + (size_t)((h) * 128) * D + (T) * 64; \
    unsigned short* d_ = (sbuf) + (((T) & 1) * 16384 + (h) * 8192 + dstw); \
    gload_lds16(g_, d_); \
    gload_lds16(g_ + 64 * D, d_ + 4096); } while (0)

#define LD8(buf, off) __builtin_bit_cast(bf16x8, *(const u16x8*)((buf) + (off)))

  STAGE(gA, sA, 0, 0); STAGE(gA, sA, 0, 1);
  STAGE(gB, sB, 0, 0); STAGE(gB, sB, 0, 1);
  asm volatile("s_waitcnt vmcnt(0)" ::: "memory");
  __builtin_amdgcn_s_barrier();

  const int NT = D / 64;  // 32
#pragma unroll 1
  for (int kt = 0; kt < NT; ++kt) {
    const unsigned short* bufA = sA + (kt & 1) * 16384;
    const unsigned short* bufB = sB + (kt & 1) * 16384;
    bf16x8 a[4][2], b0[2][2], b1[2][2];

    // ---- P0: read A03 + B01 frags; stage kt+1.A0, kt+1.A1
    #pragma unroll
    for (int i = 0; i < 4; ++i) {
      a[i][0] = LD8(bufA, arow + i * 1024 + gsw0);
      a[i][1] = LD8(bufA, arow + i * 1024 + gsw1);
    }
    #pragma unroll
    for (int j = 0; j < 2; ++j) {
      b0[j][0] = LD8(bufB, brow + j * 1024 + gsw0);
      b0[j][1] = LD8(bufB, brow + j * 1024 + gsw1);
    }
    if (kt + 1 < NT) { STAGE(gA, sA, kt + 1, 0); STAGE(gA, sA, kt + 1, 1); }
    __builtin_amdgcn_s_barrier();
    asm volatile("s_waitcnt lgkmcnt(0)" ::: "memory");
    __builtin_amdgcn_s_setprio(1);
    #pragma unroll
    for (int i = 0; i < 4; ++i)
      #pragma unroll
      for (int j = 0; j < 2; ++j) {
        acc[i][j] = __builtin_amdgcn_mfma_f32_16x16x32_bf16(a[i][0], b0[j][0], acc[i][j], 0, 0, 0);
        acc[i][j] = __builtin_amdgcn_mfma_f32_16x16x32_bf16(a[i][1], b0[j][1], acc[i][j], 0, 0, 0);
      }
    __builtin_amdgcn_s_setprio(0);
    __builtin_amdgcn_s_barrier();

    // ---- P1: read B23; stage kt+1.B0; MFMA Q(0,1)
    #pragma unroll
    for (int j = 0; j < 2; ++j) {
      b1[j][0] = LD8(bufB, brow + (j + 2) * 1024 + gsw0);
      b1[j][1] = LD8(bufB, brow + (j + 2) * 1024 + gsw1);
    }
    if (kt + 1 < NT) STAGE(gB, sB, kt + 1, 0);
    __builtin_amdgcn_s_barrier();
    asm volatile("s_waitcnt lgkmcnt(0)" ::: "memory");
    __builtin_amdgcn_s_setprio(1);
    #pragma unroll
    for (int i = 0; i < 4; ++i)
      #pragma unroll
      for (int j = 0; j < 2; ++j) {
        acc[i][j + 2] = __builtin_amdgcn_mfma_f32_16x16x32_bf16(a[i][0], b1[j][0], acc[i][j + 2], 0, 0, 0);
        acc[i][j + 2] = __builtin_amdgcn_mfma_f32_16x16x32_bf16(a[i][1], b1[j][1], acc[i][j + 2], 0, 0, 0);
      }
    __builtin_amdgcn_s_setprio(0);
    __builtin_amdgcn_s_barrier();

    // ---- P2: read A47 (reuse regs); stage kt+1.B1; MFMA Q(1,1)
    #pragma unroll
    for (int i = 0; i < 4; ++i) {
      a[i][0] = LD8(bufA, arow + (i + 4) * 1024 + gsw0);
      a[i][1] = LD8(bufA, arow + (i + 4) * 1024 + gsw1);
    }
    if (kt + 1 < NT) STAGE(gB, sB, kt + 1, 1);
    __builtin_amdgcn_s_barrier();
    asm volatile("s_waitcnt lgkmcnt(0)" ::: "memory");
    __builtin_amdgcn_s_setprio(1);
    #pragma unroll
    for (int i = 0; i < 4; ++i)
      #pragma unroll
      for (int j = 0; j < 2; ++j) {
        acc[i + 4][j + 2] = __builtin_amdgcn_mfma_f32_16x16x32_bf16(a[i][0], b1[j][0], acc[i + 4][j + 2], 0, 0, 0);
        acc[i + 4][j + 2] = __builtin_amdgcn_mfma_f32_16x16x32_bf16(a[i][1], b1[j][1], acc[i + 4][j + 2], 0, 0, 0);
      }
    __builtin_amdgcn_s_setprio(0);
    __builtin_amdgcn_s_barrier();

    // ---- P3: no reads/stages; MFMA Q(1,0); drain
    __builtin_amdgcn_s_setprio(1);
    #pragma unroll
    for (int i = 0; i < 4; ++i)
      #pragma unroll
      for (int j = 0; j < 2; ++j) {
        acc[i + 4][j] = __builtin_amdgcn_mfma_f32_16x16x32_bf16(a[i][0], b0[j][0], acc[i + 4][j], 0, 0, 0);
        acc[i + 4][j] = __builtin_amdgcn_mfma_f32_16x16x32_bf16(a[i][1], b0[j][1], acc[i + 4][j], 0, 0, 0);
      }
    __builtin_amdgcn_s_setprio(0);
    asm volatile("s_waitcnt vmcnt(0)" ::: "memory");
    __builtin_amdgcn_s_barrier();
  }

  // epilogue: dt = h @ W2^T + b2 (rank-64), out = acc*dt + Dp
  bf16x8 wb0[4], wb1[4];
  float b2v[4], dpv[4];
#pragma unroll
  for (int j = 0; j < 4; ++j) {
    int n = n0 + wn * 64 + j * 16 + lm;
    const u16x8* wp = (const u16x8*)(w2bf + (size_t)n * R + lk * 8);
    wb0[j] = __builtin_bit_cast(bf16x8, wp[0]);
    wb1[j] = __builtin_bit_cast(bf16x8, wp[4]);  // +32 bf16
    b2v[j] = b2[n];
    dpv[j] = dp[n];
  }
#pragma unroll
  for (int mi = 0; mi < 8; ++mi) {
    int hrow = m0 + wm * 128 + mi * 16 + lm;
    const u16x8* hp = (const u16x8*)(hbf + (size_t)hrow * R + lk * 8);
    bf16x8 ha0 = __builtin_bit_cast(bf16x8, hp[0]);
    bf16x8 ha1 = __builtin_bit_cast(bf16x8, hp[4]);
    int mbase = m0 + wm * 128 + mi * 16 + lk * 4;
#pragma unroll
    for (int j = 0; j < 4; ++j) {
      f32x4 dt = {};
      dt = __builtin_amdgcn_mfma_f32_16x16x32_bf16(ha0, wb0[j], dt, 0, 0, 0);
      dt = __builtin_amdgcn_mfma_f32_16x16x32_bf16(ha1, wb1[j], dt, 0, 0, 0);
      int n = n0 + wn * 64 + j * 16 + lm;
#pragma unroll
      for (int r = 0; r < 4; ++r) {
        float val = acc[mi][j][r] * (dt[r] + b2v[j]) + dpv[j];
        out[(size_t)(mbase + r) * D + n] = val;
      }
    }
  }
#undef STAGE
#undef LD8
}

extern "C" void kernel_launch(void* const* d_in, const int* in_sizes, int n_in,
                              void* d_out, int out_size, void* d_ws, size_t ws_size,
                              hipStream_t stream) {
  const float* x  = (const float*)d_in[0];
  const float* A  = (const float*)d_in[1];
  const float* B  = (const float*)d_in[2];
  const float* C  = (const float*)d_in[3];
  const float* Dp = (const float*)d_in[4];
  const float* W1 = (const float*)d_in[5];
  const float* b1 = (const float*)d_in[6];
  const float* W2 = (const float*)d_in[7];
  const float* b2 = (const float*)d_in[8];
  float* out = (float*)d_out;

  uint8_t* ws = (uint8_t*)d_ws;
  unsigned short* xbf  = (unsigned short*)ws;                                // 32 MB
  unsigned short* st   = (unsigned short*)(ws + (32u << 20));                // 8 MB
  unsigned short* w2bf = (unsigned short*)(ws + (40u << 20));                // 256 KB
  unsigned short* hbf  = (unsigned short*)(ws + (41u << 20));                // 1 MB

  prep_kernel<<<644, 512, 0, stream>>>(x, A, B, C, W1, b1, W2, xbf, st, w2bf, hbf);
  gemm_kernel<<<256, 512, 0, stream>>>(xbf, st, hbf, w2bf, b2, Dp, out);
}

// Round 6
// 100.173 us; speedup vs baseline: 1.5675x; 1.5675x over previous
//
#include <hip/hip_runtime.h>
#include <stdint.h>

#define D 2048
#define R 64
#define M_TOTAL 8192

typedef float f32x4 __attribute__((ext_vector_type(4)));
typedef __bf16 bf16x8 __attribute__((ext_vector_type(8)));
typedef unsigned short u16x8 __attribute__((ext_vector_type(8)));
typedef unsigned short u16x4 __attribute__((ext_vector_type(4)));

__device__ __forceinline__ unsigned short f2bf(float f) {
  unsigned u = __builtin_bit_cast(unsigned, f);
  u += 0x7FFFu + ((u >> 16) & 1u);
  return (unsigned short)(u >> 16);
}

__device__ __forceinline__ u16x8 pack8(float4 a, float4 b) {
  u16x8 o = { f2bf(a.x), f2bf(a.y), f2bf(a.z), f2bf(a.w),
              f2bf(b.x), f2bf(b.y), f2bf(b.z), f2bf(b.w) };
  return o;
}

__device__ __forceinline__ void gload_lds16(const void* g, void* l) {
  __builtin_amdgcn_global_load_lds(
      (const __attribute__((address_space(1))) void*)g,
      (__attribute__((address_space(3))) void*)l, 16, 0, 0);
}

// ---------------- fused prep (512 threads/block) ----------------
// blocks 0..255  : h = bf16(gelu(x@W1^T+b1)) from f32 x, ALSO writes xbf.
//                  32 rows/block; 8 waves = 4 K-quarters x 2 row-groups;
//                  16-iter loop, 2-deep STATIC-indexed register prefetch
//                  (rule #20: parity via literal macro arg), 4-way kq reduce.
// blocks 256..767: St[n][k] = bf16(A[k][n]+B[k][n]+C[k][n]), 128x64 tiles.
// blocks 768..771: W2 f32->bf16.
__global__ __launch_bounds__(512) void prep_kernel(
    const float* __restrict__ x, const float* __restrict__ A,
    const float* __restrict__ B, const float* __restrict__ C,
    const float* __restrict__ w1, const float* __restrict__ b1,
    const float* __restrict__ w2,
    unsigned short* __restrict__ xbf, unsigned short* __restrict__ st,
    unsigned short* __restrict__ w2bf, unsigned short* __restrict__ hbf) {
  __shared__ unsigned short plds[24576];  // 48 KB shared by roles
  const int t = threadIdx.x;
  const int bx = blockIdx.x;

  if (bx < 256) {
    // ---- h + x-conv ----
    unsigned short* sX = plds;         // [4 kq][2 buf][32 rows][32 k] = 16 KB
    unsigned short* sW = plds + 8192;  // [4 kq][2 buf][64 rows][32 k] = 32 KB
    const int m0 = bx * 32;
    // staging view
    const int kq = t >> 7, u = t & 127;
    const int row = u >> 2, c = u & 3;          // x: 32 rows x 4 granules
    const int row_w = u >> 1, cw0 = (u & 1) * 2; // w1: 64 rows x 2 granules/thr
    const float* xp = x + (size_t)(m0 + row) * D + kq * 512 + c * 8;
    const float* wp = w1 + (size_t)row_w * D + kq * 512 + cw0 * 8;
    unsigned short* xw = xbf + (size_t)(m0 + row) * D + kq * 512 + c * 8;
    unsigned short* sXw = sX + kq * 2048 + row * 32 + (c ^ ((row >> 1) & 3)) * 8;
    const int rw2 = (row_w >> 1) & 3;
    unsigned short* sWw0 = sW + kq * 4096 + row_w * 32 + (cw0 ^ rw2) * 8;
    unsigned short* sWw1 = sW + kq * 4096 + row_w * 32 + ((cw0 + 1) ^ rw2) * 8;
    // mfma view: wave w -> (kq quarter, row-group of 16)
    const int w = t >> 6, l = t & 63, lm = l & 15, lk = l >> 4;
    const int kqw = w >> 1, rg = w & 1;
    const int rslot = (lk ^ ((lm >> 1) & 3)) * 8;
    const unsigned short* sXr = sX + kqw * 2048 + (rg * 16 + lm) * 32 + rslot;
    const unsigned short* sWr = sW + kqw * 4096 + lm * 32 + rslot;

    f32x4 acc[4] = {};
    float4 qx[2][2], qw[2][4];
#define HLOADX(P, KT) do { qx[P][0] = *(const float4*)(xp + (KT) * 32); \
                           qx[P][1] = *(const float4*)(xp + (KT) * 32 + 4); } while (0)
#define HLOADW(P, KT) do { qw[P][0] = *(const float4*)(wp + (KT) * 32); \
                           qw[P][1] = *(const float4*)(wp + (KT) * 32 + 4); \
                           qw[P][2] = *(const float4*)(wp + (KT) * 32 + 8); \
                           qw[P][3] = *(const float4*)(wp + (KT) * 32 + 12); } while (0)
    HLOADX(0, 0); HLOADW(0, 0); HLOADX(1, 1); HLOADW(1, 1);
#define HSTEP(P, KT) do { \
    u16x8 ox = pack8(qx[P][0], qx[P][1]); \
    *(u16x8*)(sXw + (P) * 1024) = ox; \
    *(u16x8*)(xw + (KT) * 32) = ox; \
    *(u16x8*)(sWw0 + (P) * 2048) = pack8(qw[P][0], qw[P][1]); \
    *(u16x8*)(sWw1 + (P) * 2048) = pack8(qw[P][2], qw[P][3]); \
    if ((KT) + 2 < 16) { HLOADX(P, (KT) + 2); HLOADW(P, (KT) + 2); } \
    __syncthreads(); \
    { bf16x8 a_ = __builtin_bit_cast(bf16x8, *(const u16x8*)(sXr + (P) * 1024)); \
      _Pragma("unroll") \
      for (int j = 0; j < 4; ++j) { \
        bf16x8 b_ = __builtin_bit_cast(bf16x8, *(const u16x8*)(sWr + (P) * 2048 + j * 512)); \
        acc[j] = __builtin_amdgcn_mfma_f32_16x16x32_bf16(a_, b_, acc[j], 0, 0, 0); \
      } } } while (0)
#pragma unroll 1
    for (int it = 0; it < 8; ++it) { HSTEP(0, it * 2); HSTEP(1, it * 2 + 1); }
#undef HSTEP
#undef HLOADX
#undef HLOADW

    // reduce over kq (4-way): red[(kq-1)][rg][j][l] f32x4, 24 KB
    __syncthreads();
    float* red = (float*)plds;
    if (kqw > 0) {
#pragma unroll
      for (int j = 0; j < 4; ++j)
        *(f32x4*)(red + (((((kqw - 1) * 2 + rg) * 4) + j) * 64 + l) * 4) = acc[j];
    }
    __syncthreads();
    if (kqw == 0) {
      int m_base = m0 + rg * 16 + lk * 4;
#pragma unroll
      for (int j = 0; j < 4; ++j) {
        f32x4 s = acc[j];
#pragma unroll
        for (int q = 1; q < 4; ++q)
          s += *(const f32x4*)(red + (((((q - 1) * 2 + rg) * 4) + j) * 64 + l) * 4);
        int n = j * 16 + lm;
        float bv = b1[n];
#pragma unroll
        for (int r = 0; r < 4; ++r) {
          float v = s[r] + bv;
          float g = 0.5f * v * (1.0f + erff(v * 0.70710678118654752f));
          hbf[(size_t)(m_base + r) * R + n] = f2bf(g);
        }
      }
    }
  } else if (bx < 768) {
    // ---- sumt: 128(k) x 64(n) tiles ----
    unsigned short (*lds)[68] = (unsigned short(*)[68])plds;
    const int id = bx - 256;
    const int k0 = (id >> 5) * 128, n0 = (id & 31) * 64;
#pragma unroll
    for (int q = 0; q < 4; ++q) {
      int rowq = q * 32 + (t >> 4);
      int col = (t & 15) * 4;
      size_t off = (size_t)(k0 + rowq) * D + n0 + col;
      float4 a = *(const float4*)(A + off);
      float4 b = *(const float4*)(B + off);
      float4 cc = *(const float4*)(C + off);
      u16x4 o = { f2bf(a.x + b.x + cc.x), f2bf(a.y + b.y + cc.y),
                  f2bf(a.z + b.z + cc.z), f2bf(a.w + b.w + cc.w) };
      *(u16x4*)(&lds[rowq][col]) = o;
    }
    __syncthreads();
    const int n = t >> 3, kc = (t & 7) * 16;
    u16x8 v0, v1;
#pragma unroll
    for (int jj = 0; jj < 8; ++jj) v0[jj] = lds[kc + jj][n];
#pragma unroll
    for (int jj = 0; jj < 8; ++jj) v1[jj] = lds[kc + 8 + jj][n];
    size_t ooff = (size_t)(n0 + n) * D + k0 + kc;
    *(u16x8*)(st + ooff) = v0;
    *(u16x8*)(st + ooff + 8) = v1;
  } else {
    // ---- W2 conv ----
    const int NW4 = (D * R) / 4;  // 32768
    for (int i = (bx - 768) * 512 + t; i < NW4; i += 4 * 512) {
      float4 v = ((const float4*)w2)[i];
      u16x4 o = { f2bf(v.x), f2bf(v.y), f2bf(v.z), f2bf(v.w) };
      *(u16x4*)(w2bf + (size_t)i * 4) = o;
    }
  }
}

// ---------------- main: out = (x @ S) * dt + Dp ----------------
// 256x256 tile, BK=64, 8 waves (2M x 4N), 4-phase schedule. All 4 half-tiles
// of tile kt+1 staged EARLY in tile kt (A0,A1 @P0; B0 @P1; B1 @P2) so the
// single end-of-tile drain has >=1.5 phases of issue-to-wait distance.
__global__ __launch_bounds__(512, 2) void gemm_kernel(
    const unsigned short* __restrict__ xbf, const unsigned short* __restrict__ st,
    const unsigned short* __restrict__ hbf, const unsigned short* __restrict__ w2bf,
    const float* __restrict__ b2, const float* __restrict__ dp,
    float* __restrict__ out) {
  __shared__ unsigned short sA[2 * 16384];  // 2 bufs x 256 rows x 64 k, 64 KB
  __shared__ unsigned short sB[2 * 16384];  // 64 KB
  const int tid = threadIdx.x;
  const int w = tid >> 6, l = tid & 63, lk = l >> 4, lm = l & 15;
  const int wm = w >> 2, wn = w & 3;
  int bid = blockIdx.x;
  int wg = (bid & 7) * 32 + (bid >> 3);  // bijective XCD swizzle (256 wgs)
  int mb = wg >> 3, nb = wg & 7;
  int m0 = mb * 256, n0 = nb * 256;

  const int kg = (tid & 7) ^ ((tid >> 3) & 7);
  const unsigned short* gA = xbf + (size_t)(m0 + (tid >> 3)) * D + kg * 8;
  const unsigned short* gB = st + (size_t)(n0 + (tid >> 3)) * D + kg * 8;
  const int dstw = w * 512;  // shorts; wave-uniform base (HW adds lane*16B)

  const int s7 = lm & 7;
  const int gsw0 = (lk ^ s7) * 8;        // kk=0
  const int gsw1 = ((4 | lk) ^ s7) * 8;  // kk=1
  const int arow = (wm * 128 + lm) * 64;
  const int brow = (wn * 64 + lm) * 64;

  f32x4 acc[8][4] = {};

#define STAGE(gptr, sbuf, T, h) do { \
    const unsigned short* g_ = (gptr) + (size_t)((h) * 128) * D + (T) * 64; \
    unsigned short* d_ = (sbuf) + (((T) & 1) * 16384 + (h) * 8192 + dstw); \
    gload_lds16(g_, d_); \
    gload_lds16(g_ + 64 * D, d_ + 4096); } while (0)

#define LD8(buf, off) __builtin_bit_cast(bf16x8, *(const u16x8*)((buf) + (off)))

  STAGE(gA, sA, 0, 0); STAGE(gA, sA, 0, 1);
  STAGE(gB, sB, 0, 0); STAGE(gB, sB, 0, 1);
  asm volatile("s_waitcnt vmcnt(0)" ::: "memory");
  __builtin_amdgcn_s_barrier();

  const int NT = D / 64;  // 32
#pragma unroll 1
  for (int kt = 0; kt < NT; ++kt) {
    const unsigned short* bufA = sA + (kt & 1) * 16384;
    const unsigned short* bufB = sB + (kt & 1) * 16384;
    bf16x8 a[4][2], b0[2][2], b1[2][2];

    // ---- P0: read A03 + B01 frags; stage kt+1.A0, kt+1.A1
    #pragma unroll
    for (int i = 0; i < 4; ++i) {
      a[i][0] = LD8(bufA, arow + i * 1024 + gsw0);
      a[i][1] = LD8(bufA, arow + i * 1024 + gsw1);
    }
    #pragma unroll
    for (int j = 0; j < 2; ++j) {
      b0[j][0] = LD8(bufB, brow + j * 1024 + gsw0);
      b0[j][1] = LD8(bufB, brow + j * 1024 + gsw1);
    }
    if (kt + 1 < NT) { STAGE(gA, sA, kt + 1, 0); STAGE(gA, sA, kt + 1, 1); }
    __builtin_amdgcn_s_barrier();
    asm volatile("s_waitcnt lgkmcnt(0)" ::: "memory");
    __builtin_amdgcn_s_setprio(1);
    #pragma unroll
    for (int i = 0; i < 4; ++i)
      #pragma unroll
      for (int j = 0; j < 2; ++j) {
        acc[i][j] = __builtin_amdgcn_mfma_f32_16x16x32_bf16(a[i][0], b0[j][0], acc[i][j], 0, 0, 0);
        acc[i][j] = __builtin_amdgcn_mfma_f32_16x16x32_bf16(a[i][1], b0[j][1], acc[i][j], 0, 0, 0);
      }
    __builtin_amdgcn_s_setprio(0);
    __builtin_amdgcn_s_barrier();

    // ---- P1: read B23; stage kt+1.B0; MFMA Q(0,1)
    #pragma unroll
    for (int j = 0; j < 2; ++j) {
      b1[j][0] = LD8(bufB, brow + (j + 2) * 1024 + gsw0);
      b1[j][1] = LD8(bufB, brow + (j + 2) * 1024 + gsw1);
    }
    if (kt + 1 < NT) STAGE(gB, sB, kt + 1, 0);
    __builtin_amdgcn_s_barrier();
    asm volatile("s_waitcnt lgkmcnt(0)" ::: "memory");
    __builtin_amdgcn_s_setprio(1);
    #pragma unroll
    for (int i = 0; i < 4; ++i)
      #pragma unroll
      for (int j = 0; j < 2; ++j) {
        acc[i][j + 2] = __builtin_amdgcn_mfma_f32_16x16x32_bf16(a[i][0], b1[j][0], acc[i][j + 2], 0, 0, 0);
        acc[i][j + 2] = __builtin_amdgcn_mfma_f32_16x16x32_bf16(a[i][1], b1[j][1], acc[i][j + 2], 0, 0, 0);
      }
    __builtin_amdgcn_s_setprio(0);
    __builtin_amdgcn_s_barrier();

    // ---- P2: read A47 (reuse regs); stage kt+1.B1; MFMA Q(1,1)
    #pragma unroll
    for (int i = 0; i < 4; ++i) {
      a[i][0] = LD8(bufA, arow + (i + 4) * 1024 + gsw0);
      a[i][1] = LD8(bufA, arow + (i + 4) * 1024 + gsw1);
    }
    if (kt + 1 < NT) STAGE(gB, sB, kt + 1, 1);
    __builtin_amdgcn_s_barrier();
    asm volatile("s_waitcnt lgkmcnt(0)" ::: "memory");
    __builtin_amdgcn_s_setprio(1);
    #pragma unroll
    for (int i = 0; i < 4; ++i)
      #pragma unroll
      for (int j = 0; j < 2; ++j) {
        acc[i + 4][j + 2] = __builtin_amdgcn_mfma_f32_16x16x32_bf16(a[i][0], b1[j][0], acc[i + 4][j + 2], 0, 0, 0);
        acc[i + 4][j + 2] = __builtin_amdgcn_mfma_f32_16x16x32_bf16(a[i][1], b1[j][1], acc[i + 4][j + 2], 0, 0, 0);
      }
    __builtin_amdgcn_s_setprio(0);
    __builtin_amdgcn_s_barrier();

    // ---- P3: no reads/stages; MFMA Q(1,0); drain
    __builtin_amdgcn_s_setprio(1);
    #pragma unroll
    for (int i = 0; i < 4; ++i)
      #pragma unroll
      for (int j = 0; j < 2; ++j) {
        acc[i + 4][j] = __builtin_amdgcn_mfma_f32_16x16x32_bf16(a[i][0], b0[j][0], acc[i + 4][j], 0, 0, 0);
        acc[i + 4][j] = __builtin_amdgcn_mfma_f32_16x16x32_bf16(a[i][1], b0[j][1], acc[i + 4][j], 0, 0, 0);
      }
    __builtin_amdgcn_s_setprio(0);
    asm volatile("s_waitcnt vmcnt(0)" ::: "memory");
    __builtin_amdgcn_s_barrier();
  }

  // epilogue: dt = h @ W2^T + b2 (rank-64), out = acc*dt + Dp
  bf16x8 wb0[4], wb1[4];
  float b2v[4], dpv[4];
#pragma unroll
  for (int j = 0; j < 4; ++j) {
    int n = n0 + wn * 64 + j * 16 + lm;
    const u16x8* wp = (const u16x8*)(w2bf + (size_t)n * R + lk * 8);
    wb0[j] = __builtin_bit_cast(bf16x8, wp[0]);
    wb1[j] = __builtin_bit_cast(bf16x8, wp[4]);  // +32 bf16
    b2v[j] = b2[n];
    dpv[j] = dp[n];
  }
#pragma unroll
  for (int mi = 0; mi < 8; ++mi) {
    int hrow = m0 + wm * 128 + mi * 16 + lm;
    const u16x8* hp = (const u16x8*)(hbf + (size_t)hrow * R + lk * 8);
    bf16x8 ha0 = __builtin_bit_cast(bf16x8, hp[0]);
    bf16x8 ha1 = __builtin_bit_cast(bf16x8, hp[4]);
    int mbase = m0 + wm * 128 + mi * 16 + lk * 4;
#pragma unroll
    for (int j = 0; j < 4; ++j) {
      f32x4 dt = {};
      dt = __builtin_amdgcn_mfma_f32_16x16x32_bf16(ha0, wb0[j], dt, 0, 0, 0);
      dt = __builtin_amdgcn_mfma_f32_16x16x32_bf16(ha1, wb1[j], dt, 0, 0, 0);
      int n = n0 + wn * 64 + j * 16 + lm;
#pragma unroll
      for (int r = 0; r < 4; ++r) {
        float val = acc[mi][j][r] * (dt[r] + b2v[j]) + dpv[j];
        out[(size_t)(mbase + r) * D + n] = val;
      }
    }
  }
#undef STAGE
#undef LD8
}

extern "C" void kernel_launch(void* const* d_in, const int* in_sizes, int n_in,
                              void* d_out, int out_size, void* d_ws, size_t ws_size,
                              hipStream_t stream) {
  const float* x  = (const float*)d_in[0];
  const float* A  = (const float*)d_in[1];
  const float* B  = (const float*)d_in[2];
  const float* C  = (const float*)d_in[3];
  const float* Dp = (const float*)d_in[4];
  const float* W1 = (const float*)d_in[5];
  const float* b1 = (const float*)d_in[6];
  const float* W2 = (const float*)d_in[7];
  const float* b2 = (const float*)d_in[8];
  float* out = (float*)d_out;

  uint8_t* ws = (uint8_t*)d_ws;
  unsigned short* xbf  = (unsigned short*)ws;                                // 32 MB
  unsigned short* st   = (unsigned short*)(ws + (32u << 20));                // 8 MB
  unsigned short* w2bf = (unsigned short*)(ws + (40u << 20));                // 256 KB
  unsigned short* hbf  = (unsigned short*)(ws + (41u << 20));                // 1 MB

  prep_kernel<<<772, 512, 0, stream>>>(x, A, B, C, W1, b1, W2, xbf, st, w2bf, hbf);
  gemm_kernel<<<256, 512, 0, stream>>>(xbf, st, hbf, w2bf, b2, Dp, out);
}